// Round 9
// baseline (516.671 us; speedup 1.0000x reference)
//
#include <hip/hip_runtime.h>
#include <hip/hip_bf16.h>

#define NN 100000      // nodes
#define NE 200000      // edges
#define NF 56          // atom feats
#define HD 256         // hidden
#define NG 2048        // graphs

#define SCAN_CH 512
#define NCH ((NN + SCAN_CH - 1) / SCAN_CH)   // 196 chunks
#define EB ((NE + 255) / 256)                // csr_fill edge blocks

#define ZB 98          // deg-zero blocks in prep_params (25000 int4 / 256)
#define CVB ((NN + 255) / 256)               // x->bf16 convert blocks (391)
#define ENB ((NN + 127) / 128)               // 128-row encoder blocks (782)
#define GM  32                               // layer-1 M-tile
#define GNB (NN / GM)                        // 3125 blocks (exact: 32*3125=100000)

typedef __bf16 bf16x8 __attribute__((ext_vector_type(8)));
typedef __bf16 bf16x4 __attribute__((ext_vector_type(4)));
typedef float  floatx4 __attribute__((ext_vector_type(4)));

// ---- param prep (fully merged) ----------------------------------------------
__global__ void prep_params(const float* __restrict__ emb, const float* __restrict__ Ws,
                            const float* __restrict__ bs, const float* __restrict__ lw,
                            __bf16* __restrict__ dW0t,
                            float* __restrict__ w2lw, float* __restrict__ b2lw,
                            __bf16* __restrict__ Wt, unsigned* __restrict__ deg,
                            const int* __restrict__ x, __bf16* __restrict__ xb) {
    __shared__ float row[HD];
    int c = threadIdx.x;
    int f = blockIdx.x;
    if (f >= NF + 2) {
        int g = f - (NF + 2);
        if (g < HD) {       // Wt[n=g][k=c] = Ws[1][c][g]
            Wt[(size_t)g * HD + c] = (__bf16)Ws[(size_t)HD * HD + (size_t)c * HD + g];
        } else if (g < HD + ZB) {   // zero deg as int4
            int idx = (g - HD) * HD + c;
            if (idx < NN / 4) ((int4*)deg)[idx] = make_int4(0, 0, 0, 0);
        } else {            // x -> bf16 pad-64 convert, col 56 = 1
            int r = (g - HD - ZB) * 256 + c;
            if (r < NN) {
                const int* xr = x + (size_t)r * NF;
                __bf16 o[64];
                #pragma unroll
                for (int j = 0; j < 14; ++j) {
                    int4 iv = *(const int4*)&xr[j * 4];
                    o[j * 4 + 0] = (__bf16)(float)iv.x;
                    o[j * 4 + 1] = (__bf16)(float)iv.y;
                    o[j * 4 + 2] = (__bf16)(float)iv.z;
                    o[j * 4 + 3] = (__bf16)(float)iv.w;
                }
                o[56] = (__bf16)1.0f;
                #pragma unroll
                for (int j = 57; j < 64; ++j) o[j] = (__bf16)0.0f;
                #pragma unroll
                for (int j = 0; j < 8; ++j)
                    *(bf16x8*)&xb[(size_t)r * 64 + j * 8] = *(const bf16x8*)&o[j * 8];
            }
        }
        return;
    }
    if (f == NF + 1) {   // layer-2 collapse params
        const float* W2 = Ws + (size_t)2 * HD * HD;
        float acc = 0.f;
        for (int k = 0; k < HD; ++k) acc += W2[(size_t)c * HD + k] * lw[k];
        w2lw[c] = acc;
        row[c] = bs[2 * HD + c] * lw[c];
        __syncthreads();
        for (int off = 128; off > 0; off >>= 1) {
            if (c < off) row[c] += row[c + off];
            __syncthreads();
        }
        if (c == 0) *b2lw = row[0];
        return;
    }
    if (f < NF) {
        row[c] = emb[(f * 2 + 1) * HD + c] - emb[(f * 2 + 0) * HD + c];
    } else {
        float s = 0.f;
        for (int ff = 0; ff < NF; ++ff) s += emb[(ff * 2) * HD + c];
        row[c] = s;
    }
    __syncthreads();
    float acc = 0.f;
    for (int k = 0; k < HD; ++k) acc += row[k] * Ws[k * HD + c];   // W0
    if (f < NF) {
        dW0t[c * 64 + f] = (__bf16)acc;          // transposed bf16, direct
    } else {
        dW0t[c * 64 + 56] = (__bf16)acc;         // base row via rowsum column
        #pragma unroll
        for (int k = 57; k < 64; ++k) dW0t[c * 64 + k] = (__bf16)0.f;
    }
}

// ---- degree ------------------------------------------------------------------
__global__ void deg_kernel(const int* __restrict__ dst, unsigned* __restrict__ deg, int E) {
    int e = blockIdx.x * blockDim.x + threadIdx.x;
    if (e < E) atomicAdd(&deg[dst[e]], 1u);
}

// merged: per-chunk degree sum (for scan) + dinv/selfn
__global__ void chunk_sum_dinv(const unsigned* __restrict__ deg, unsigned* __restrict__ csum,
                               float* __restrict__ dinv, float* __restrict__ selfn) {
    __shared__ unsigned s[SCAN_CH];
    int t = threadIdx.x;
    int base = blockIdx.x * SCAN_CH;
    unsigned v = (base + t < NN) ? deg[base + t] : 0u;
    s[t] = v;
    if (base + t < NN) {
        float d = (float)(v + 1u);   // +1 self loop
        dinv[base + t]  = rsqrtf(d);
        selfn[base + t] = 1.0f / d;
    }
    __syncthreads();
    for (int off = SCAN_CH / 2; off > 0; off >>= 1) {
        if (t < off) s[t] += s[t + off];
        __syncthreads();
    }
    if (t == 0) csum[blockIdx.x] = s[0];
}

// chunk_apply with INLINE scan of csum (each block re-scans 196 chunk sums)
__global__ void chunk_apply(const unsigned* __restrict__ deg, const unsigned* __restrict__ csum,
                            unsigned* __restrict__ row_start, unsigned* __restrict__ cursor) {
    __shared__ unsigned s[SCAN_CH];
    __shared__ unsigned cs[256];
    int t = threadIdx.x;
    if (t < 256) cs[t] = (t < NCH) ? csum[t] : 0u;
    __syncthreads();
    for (int off = 1; off < 256; off <<= 1) {
        unsigned add = (t < 256 && t >= off) ? cs[t - off] : 0u;
        __syncthreads();
        if (t < 256) cs[t] += add;
        __syncthreads();
    }
    unsigned chunk_base = (blockIdx.x == 0) ? 0u : cs[blockIdx.x - 1];

    int base = blockIdx.x * SCAN_CH;
    unsigned v = (base + t < NN) ? deg[base + t] : 0u;
    s[t] = v;
    __syncthreads();
    for (int off = 1; off < SCAN_CH; off <<= 1) {
        unsigned add = (t >= off) ? s[t - off] : 0u;
        __syncthreads();
        s[t] += add;
        __syncthreads();
    }
    if (base + t < NN) {
        unsigned rs = chunk_base + s[t] - v;   // exclusive scan value
        row_start[base + t] = rs;
        cursor[base + t] = rs;
    }
    if (blockIdx.x == 0 && t == 0) row_start[NN] = NE;
}

// csr_fill (inline norm) + graph_bounds merged into the tail blocks
__global__ void csr_fill_gb(const int* __restrict__ src, const int* __restrict__ dst,
                            const float* __restrict__ dinv, unsigned* __restrict__ cursor,
                            int* __restrict__ ecol, float* __restrict__ enorm,
                            const int* __restrict__ batch, unsigned* __restrict__ gstart) {
    int t = threadIdx.x;
    if (blockIdx.x < EB) {
        int e = blockIdx.x * 256 + t;
        if (e < NE) {
            int s = src[e], d = dst[e];
            unsigned pos = atomicAdd(&cursor[d], 1u);
            ecol[pos] = s;
            enorm[pos] = dinv[s] * dinv[d];
        }
    } else {
        int g = (blockIdx.x - EB) * 256 + t;
        if (g <= NG) {
            int lo = 0, hi = NN;
            while (lo < hi) {
                int mid = (lo + hi) >> 1;
                if (batch[mid] < g) lo = mid + 1; else hi = mid;
            }
            gstart[g] = (unsigned)lo;
        }
    }
}

// ---- fused layer-0: aggregate S.xb into LDS A-tile, then GEMM + BN stats ----
#define ELSTR 68
__global__ void __launch_bounds__(512) enc_fused(const __bf16* __restrict__ xb,
                                                 const __bf16* __restrict__ dW0t,
                                                 const float* __restrict__ b0,
                                                 const float* __restrict__ selfn,
                                                 const unsigned* __restrict__ row_start,
                                                 const int* __restrict__ ecol,
                                                 const float* __restrict__ enorm,
                                                 __bf16* __restrict__ C,
                                                 float* __restrict__ part) {
    __shared__ __bf16 sA[128 * ELSTR];   // 17408 B (aggregated A-tile)
    __shared__ __bf16 sB[256 * ELSTR];   // 34816 B
    __shared__ float psum[8][64];        // 2 KB
    __shared__ float psq[8][64];         // 2 KB
    int t = threadIdx.x;
    int m0 = blockIdx.x * 128;
    int lane = t & 63, w = t >> 6;
    int quad = lane >> 4, l16 = lane & 15;
    int mw = (w & 1) * 64, nw = (w >> 1) * 64;

    {   // B stage: 256 rows x 64 cols bf16
        int bn = t >> 1;
        int kh = (t & 1) * 32;
        #pragma unroll
        for (int j = 0; j < 4; ++j)
            *(bf16x8*)&sB[bn * ELSTR + kh + j * 8] =
                *(const bf16x8*)&dW0t[(size_t)bn * 64 + kh + j * 8];
    }
    {   // A stage = in-place aggregation: 4 threads per node, 16 cols each
        int r = t >> 2;
        int p = (t & 3) * 16;
        int n = m0 + r;
        float acc[16];
        #pragma unroll
        for (int i = 0; i < 16; ++i) acc[i] = 0.f;
        if (n < NN) {
            float sn = selfn[n];
            bf16x8 a0 = *(const bf16x8*)&xb[(size_t)n * 64 + p];
            bf16x8 a1 = *(const bf16x8*)&xb[(size_t)n * 64 + p + 8];
            #pragma unroll
            for (int i = 0; i < 8; ++i) {
                acc[i]     = (float)a0[i] * sn;
                acc[8 + i] = (float)a1[i] * sn;
            }
            unsigned e0 = row_start[n], e1 = row_start[n + 1];
            unsigned e = e0;
            for (; e + 2 <= e1; e += 2) {
                int s0 = ecol[e], s1 = ecol[e + 1];
                float n0v = enorm[e], n1v = enorm[e + 1];
                bf16x8 u00 = *(const bf16x8*)&xb[(size_t)s0 * 64 + p];
                bf16x8 u01 = *(const bf16x8*)&xb[(size_t)s0 * 64 + p + 8];
                bf16x8 u10 = *(const bf16x8*)&xb[(size_t)s1 * 64 + p];
                bf16x8 u11 = *(const bf16x8*)&xb[(size_t)s1 * 64 + p + 8];
                #pragma unroll
                for (int i = 0; i < 8; ++i) {
                    acc[i]     += (float)u00[i] * n0v + (float)u10[i] * n1v;
                    acc[8 + i] += (float)u01[i] * n0v + (float)u11[i] * n1v;
                }
            }
            if (e < e1) {
                int s0 = ecol[e];
                float n0v = enorm[e];
                bf16x8 u00 = *(const bf16x8*)&xb[(size_t)s0 * 64 + p];
                bf16x8 u01 = *(const bf16x8*)&xb[(size_t)s0 * 64 + p + 8];
                #pragma unroll
                for (int i = 0; i < 8; ++i) {
                    acc[i]     += (float)u00[i] * n0v;
                    acc[8 + i] += (float)u01[i] * n0v;
                }
            }
        }
        bf16x8 o0, o1;
        #pragma unroll
        for (int i = 0; i < 8; ++i) { o0[i] = (__bf16)acc[i]; o1[i] = (__bf16)acc[8 + i]; }
        *(bf16x8*)&sA[r * ELSTR + p]     = o0;
        *(bf16x8*)&sA[r * ELSTR + p + 8] = o1;
    }
    __syncthreads();

    floatx4 acc[4][4] = {};
    #pragma unroll
    for (int s = 0; s < 2; ++s) {
        bf16x8 af[4], bfr[4];
        #pragma unroll
        for (int i = 0; i < 4; ++i)
            af[i] = *(const bf16x8*)&sA[(mw + i * 16 + l16) * ELSTR + s * 32 + quad * 8];
        #pragma unroll
        for (int i = 0; i < 4; ++i)
            bfr[i] = *(const bf16x8*)&sB[(nw + i * 16 + l16) * ELSTR + s * 32 + quad * 8];
        #pragma unroll
        for (int mi = 0; mi < 4; ++mi)
            #pragma unroll
            for (int ni = 0; ni < 4; ++ni)
                acc[mi][ni] = __builtin_amdgcn_mfma_f32_16x16x32_bf16(
                    af[mi], bfr[ni], acc[mi][ni], 0, 0, 0);
    }

    float bw[4];
    #pragma unroll
    for (int ni = 0; ni < 4; ++ni) bw[ni] = b0[nw + ni * 16 + l16];
    float ls[4] = {0.f, 0.f, 0.f, 0.f};
    float lq[4] = {0.f, 0.f, 0.f, 0.f};
    #pragma unroll
    for (int mi = 0; mi < 4; ++mi) {
        #pragma unroll
        for (int r = 0; r < 4; ++r) {
            int row = m0 + mw + mi * 16 + quad * 4 + r;
            if (row < NN) {
                #pragma unroll
                for (int ni = 0; ni < 4; ++ni) {
                    float v = acc[mi][ni][r] + bw[ni];
                    C[(size_t)row * HD + nw + ni * 16 + l16] = (__bf16)v;
                    ls[ni] += v;
                    lq[ni] += v * v;
                }
            }
        }
    }
    // reduce across quads (rows) -> lanes 0..15 hold per-column partials
    #pragma unroll
    for (int ni = 0; ni < 4; ++ni) {
        ls[ni] += __shfl_xor(ls[ni], 16, 64);
        ls[ni] += __shfl_xor(ls[ni], 32, 64);
        lq[ni] += __shfl_xor(lq[ni], 16, 64);
        lq[ni] += __shfl_xor(lq[ni], 32, 64);
    }
    if (lane < 16) {
        #pragma unroll
        for (int ni = 0; ni < 4; ++ni) {
            psum[w][ni * 16 + l16] = ls[ni];
            psq[w][ni * 16 + l16]  = lq[ni];
        }
    }
    __syncthreads();
    if (!(w & 1) && lane < 16) {   // combine the two mw waves sharing nw
        #pragma unroll
        for (int ni = 0; ni < 4; ++ni) {
            int ci = ni * 16 + l16;
            part[(size_t)blockIdx.x * 512 + nw + ci]       = psum[w][ci] + psum[w + 1][ci];
            part[(size_t)blockIdx.x * 512 + 256 + nw + ci] = psq[w][ci]  + psq[w + 1][ci];
        }
    }
}

// ---- fused layer-1 v3: EDGE-PARALLEL aggregation + GEMM + BN stats ----------
// Phase A: block's CSR edge range is contiguous; waves process independent
// edges (2-wide pipeline, chain-free gathers), dst row found by 5-step LDS
// binary search (wave-uniform), accumulate via native LDS f32 atomicAdd.
// Self-term seeds the f32 tile with plain coalesced stores.
// Phase B: B-slice lives in 64 VGPRs per wave (preloaded, overlaps phase A) —
// no sB, no per-chunk barriers. f32 tile converted in-place to swizzled bf16.
__global__ void __launch_bounds__(512) gcn_fused(const __bf16* __restrict__ h0,
                                                 const float* __restrict__ scale,
                                                 const float* __restrict__ shift,
                                                 const __bf16* __restrict__ Wt,
                                                 const float* __restrict__ b1,
                                                 const float* __restrict__ selfn,
                                                 const unsigned* __restrict__ row_start,
                                                 const int* __restrict__ ecol,
                                                 const float* __restrict__ enorm,
                                                 __bf16* __restrict__ C,
                                                 float* __restrict__ part) {
    __shared__ float sAf[GM * 256];      // 32 KB f32 accum; low 16 KB reused as bf16 tile
    __shared__ unsigned rs[GM + 1];
    int t = threadIdx.x;
    int m0 = blockIdx.x * GM;
    int lane = t & 63, w = t >> 6;
    int quad = lane >> 4, l16 = lane & 15;
    int c4 = lane * 4;

    if (t <= GM) rs[t] = row_start[m0 + t];

    // B-slice into registers: wave w owns output cols [w*32, w*32+32), K=256.
    bf16x8 breg[8][2];
    #pragma unroll
    for (int c = 0; c < 8; ++c)
        #pragma unroll
        for (int ni = 0; ni < 2; ++ni)
            breg[c][ni] = *(const bf16x8*)&Wt[(size_t)(w * 32 + ni * 16 + l16) * HD + c * 32 + quad * 8];

    float4 sc = *(const float4*)&scale[c4];
    float4 sh = *(const float4*)&shift[c4];

    // self-init: 4 rows per wave, lane covers its 4 cols (coalesced, plain stores)
    #pragma unroll
    for (int g = 0; g < 4; ++g) {
        int r = w * 4 + g;
        int n = m0 + r;                       // exact tiling: always < NN
        float sn = selfn[n];
        bf16x4 hv = *(const bf16x4*)&h0[(size_t)n * HD + c4];
        float* dp = &sAf[r * 256 + c4];
        dp[0] = fmaxf((float)hv[0] * sc.x + sh.x, 0.f) * sn;
        dp[1] = fmaxf((float)hv[1] * sc.y + sh.y, 0.f) * sn;
        dp[2] = fmaxf((float)hv[2] * sc.z + sh.z, 0.f) * sn;
        dp[3] = fmaxf((float)hv[3] * sc.w + sh.w, 0.f) * sn;
    }
    __syncthreads();

    // edge-parallel phase: wave per edge, stride 8; independent iterations
    {
        unsigned r0 = rs[0], r2 = rs[GM];
        auto edge_body = [&](unsigned e) {
            int col = ecol[e];
            float nm = enorm[e];
            int lo = 0, hi = GM;
            #pragma unroll
            for (int it = 0; it < 5; ++it) {   // 2^5 = GM
                int mid = (lo + hi) >> 1;
                if (rs[mid] <= e) lo = mid; else hi = mid;
            }
            bf16x4 u = *(const bf16x4*)&h0[(size_t)col * HD + c4];
            float* dp = &sAf[lo * 256 + c4];
            atomicAdd(dp + 0, fmaxf((float)u[0] * sc.x + sh.x, 0.f) * nm);
            atomicAdd(dp + 1, fmaxf((float)u[1] * sc.y + sh.y, 0.f) * nm);
            atomicAdd(dp + 2, fmaxf((float)u[2] * sc.z + sh.z, 0.f) * nm);
            atomicAdd(dp + 3, fmaxf((float)u[3] * sc.w + sh.w, 0.f) * nm);
        };
        unsigned e = r0 + w;
        for (; e + 8 < r2; e += 16) { edge_body(e); edge_body(e + 8); }
        if (e < r2) edge_body(e);
    }
    __syncthreads();

    // convert f32 -> swizzled bf16 tile (aliases sAf): read-all / barrier / write-all
    {
        int r = t >> 4;
        int c0 = (t & 15) * 16;
        float tmp[16];
        #pragma unroll
        for (int i = 0; i < 16; ++i) tmp[i] = sAf[r * 256 + c0 + i];
        __syncthreads();
        __bf16* sA16w = (__bf16*)sAf;
        bf16x8 o0, o1;
        #pragma unroll
        for (int i = 0; i < 8; ++i) { o0[i] = (__bf16)tmp[i]; o1[i] = (__bf16)tmp[8 + i]; }
        int g0 = c0 >> 3;
        *(bf16x8*)&sA16w[r * 256 + ((g0 ^ (r & 7)) << 3)]       = o0;
        *(bf16x8*)&sA16w[r * 256 + (((g0 + 1) ^ (r & 7)) << 3)] = o1;
    }
    __syncthreads();

    // phase B: K=256 GEMM, B from VGPRs, no barriers
    const __bf16* sA16 = (const __bf16*)sAf;
    floatx4 cacc[2][2] = {};
    #pragma unroll
    for (int c = 0; c < 8; ++c) {
        bf16x8 af[2];
        #pragma unroll
        for (int mi = 0; mi < 2; ++mi) {
            int row = mi * 16 + l16;
            int g = (c * 4 + quad) ^ (l16 & 7);
            af[mi] = *(const bf16x8*)&sA16[row * 256 + (g << 3)];
        }
        #pragma unroll
        for (int mi = 0; mi < 2; ++mi)
            #pragma unroll
            for (int ni = 0; ni < 2; ++ni)
                cacc[mi][ni] = __builtin_amdgcn_mfma_f32_16x16x32_bf16(
                    af[mi], breg[c][ni], cacc[mi][ni], 0, 0, 0);
    }

    // epilogue: bias, C-write, per-column BN partials
    float bw[2];
    #pragma unroll
    for (int ni = 0; ni < 2; ++ni) bw[ni] = b1[w * 32 + ni * 16 + l16];
    float ls[2] = {0.f, 0.f}, lq[2] = {0.f, 0.f};
    #pragma unroll
    for (int mi = 0; mi < 2; ++mi) {
        #pragma unroll
        for (int r_ = 0; r_ < 4; ++r_) {
            int row = m0 + mi * 16 + quad * 4 + r_;
            #pragma unroll
            for (int ni = 0; ni < 2; ++ni) {
                float v = cacc[mi][ni][r_] + bw[ni];
                C[(size_t)row * HD + w * 32 + ni * 16 + l16] = (__bf16)v;
                ls[ni] += v;
                lq[ni] += v * v;
            }
        }
    }
    #pragma unroll
    for (int ni = 0; ni < 2; ++ni) {
        ls[ni] += __shfl_xor(ls[ni], 16, 64);
        ls[ni] += __shfl_xor(ls[ni], 32, 64);
        lq[ni] += __shfl_xor(lq[ni], 16, 64);
        lq[ni] += __shfl_xor(lq[ni], 32, 64);
    }
    if (lane < 16) {
        #pragma unroll
        for (int ni = 0; ni < 2; ++ni) {
            int ci = w * 32 + ni * 16 + l16;
            part[(size_t)blockIdx.x * 512 + ci]       = ls[ni];
            part[(size_t)blockIdx.x * 512 + 256 + ci] = lq[ni];
        }
    }
}

// Stage 2: one block per column c; reduce nb per-block partials, emit scale/shift.
__global__ void __launch_bounds__(256) bn_scale(const float* __restrict__ part, int nb,
                                                const float* __restrict__ gamma,
                                                const float* __restrict__ beta,
                                                float* __restrict__ scale,
                                                float* __restrict__ shift) {
    __shared__ float rs[256], rq[256];
    int t = threadIdx.x;
    int c = blockIdx.x;
    float s = 0.f, q = 0.f;
    for (int j = t; j < nb; j += 256) {
        s += part[(size_t)j * 512 + c];
        q += part[(size_t)j * 512 + 256 + c];
    }
    rs[t] = s; rq[t] = q;
    __syncthreads();
    for (int off = 128; off > 0; off >>= 1) {
        if (t < off) { rs[t] += rs[t + off]; rq[t] += rq[t + off]; }
        __syncthreads();
    }
    if (t == 0) {
        const float inv_n = 1.0f / (float)NN;
        float mu  = rs[0] * inv_n;
        float var = rq[0] * inv_n - mu * mu;
        float rstd = rsqrtf(var + 1e-5f);
        float sc = gamma[c] * rstd;
        scale[c] = sc;
        shift[c] = beta[c] - mu * sc;
    }
}

// ---- layer-2 collapse: z[n] = relu_bn(h[n]) . w2lw  (one wave per node) -----
__global__ void __launch_bounds__(256) bn_dot(const __bf16* __restrict__ h,
                                              const float* __restrict__ scale,
                                              const float* __restrict__ shift,
                                              const float* __restrict__ w2lw,
                                              float* __restrict__ z) {
    int tid = blockIdx.x * 256 + threadIdx.x;
    int n = tid >> 6;
    if (n >= NN) return;
    int l = tid & 63;
    int c4 = l * 4;
    bf16x4 a = *(const bf16x4*)&h[(size_t)n * HD + c4];
    float4 sc = *(const float4*)&scale[c4];
    float4 sh = *(const float4*)&shift[c4];
    float4 wv = *(const float4*)&w2lw[c4];
    float d = fmaxf((float)a[0] * sc.x + sh.x, 0.f) * wv.x
            + fmaxf((float)a[1] * sc.y + sh.y, 0.f) * wv.y
            + fmaxf((float)a[2] * sc.z + sh.z, 0.f) * wv.z
            + fmaxf((float)a[3] * sc.w + sh.w, 0.f) * wv.w;
    #pragma unroll
    for (int off = 32; off > 0; off >>= 1) d += __shfl_down(d, off, 64);
    if (l == 0) z[n] = d;
}

// ---- fused final: per-graph wave; lanes stride nodes; scalar edge loop ------
__global__ void __launch_bounds__(256) pool_fused(const float* __restrict__ z,
                                                  const float* __restrict__ selfn,
                                                  const float* __restrict__ b2lw,
                                                  const unsigned* __restrict__ row_start,
                                                  const int* __restrict__ ecol,
                                                  const float* __restrict__ enorm,
                                                  const unsigned* __restrict__ gstart,
                                                  const float* __restrict__ lb,
                                                  float* __restrict__ out) {
    int tid = blockIdx.x * 256 + threadIdx.x;
    int g = tid >> 6;
    if (g >= NG) return;
    int l = tid & 63;
    unsigned s0 = gstart[g], s1 = gstart[g + 1];
    float bb = *b2lw;
    float s = 0.f;
    for (unsigned i = s0 + l; i < s1; i += 64) {
        float d = selfn[i] * z[i] + bb;
        unsigned e0 = row_start[i], e1 = row_start[i + 1];
        for (unsigned e = e0; e < e1; ++e)
            d += enorm[e] * z[ecol[e]];
        s += d;
    }
    #pragma unroll
    for (int off = 32; off > 0; off >>= 1) s += __shfl_down(s, off, 64);
    if (l == 0) out[g] = s / fmaxf((float)(s1 - s0), 1.0f) + lb[0];
}

// ---- driver -----------------------------------------------------------------
extern "C" void kernel_launch(void* const* d_in, const int* in_sizes, int n_in,
                              void* d_out, int out_size, void* d_ws, size_t ws_size,
                              hipStream_t stream) {
    const int*   x     = (const int*)d_in[0];
    const int*   ei    = (const int*)d_in[1];
    const int*   batch = (const int*)d_in[2];
    const float* emb   = (const float*)d_in[3];
    const float* Ws    = (const float*)d_in[4];
    const float* bs    = (const float*)d_in[5];
    const float* gam   = (const float*)d_in[6];
    const float* bet   = (const float*)d_in[7];
    const float* lw    = (const float*)d_in[8];
    const float* lb    = (const float*)d_in[9];
    float* out = (float*)d_out;

    const int* src = ei;
    const int* dst = ei + NE;

    // workspace carve-up (256-B aligned)
    char* p = (char*)d_ws;
    size_t off = 0;
    auto carve = [&](size_t bytes) { void* r = p + off; off = (off + bytes + 255) & ~(size_t)255; return r; };
    __bf16*   buf0   = (__bf16*)carve((size_t)NN * HD * 2);   // conv0 (bf16)
    __bf16*   buf1   = (__bf16*)carve((size_t)NN * HD * 2);   // conv1 (bf16)
    __bf16*   xb     = (__bf16*)carve((size_t)NN * 64 * 2);   // x as bf16, pad 64
    __bf16*   dW0t   = (__bf16*)carve(HD * 64 * 2);
    __bf16*   Wt     = (__bf16*)carve((size_t)HD * HD * 2);   // layer-1 only
    float*    w2lw   = (float*)carve(HD * 4);
    float*    b2lw   = (float*)carve(256);
    unsigned* deg    = (unsigned*)carve(NN * 4);
    float*    dinv   = (float*)carve(NN * 4);
    float*    selfn  = (float*)carve(NN * 4);
    unsigned* csum   = (unsigned*)carve(256 * 4);
    unsigned* row_s  = (unsigned*)carve((NN + 1) * 4);
    unsigned* cursor = (unsigned*)carve(NN * 4);
    int*      ecol   = (int*)carve(NE * 4);
    float*    enorm  = (float*)carve(NE * 4);
    float*    part   = (float*)carve((size_t)GNB * 512 * 4);  // 6.4 MB, [blk][512]
    float*    scale  = (float*)carve(HD * 4);
    float*    shift  = (float*)carve(HD * 4);
    unsigned* gstart = (unsigned*)carve((NG + 1) * 4);
    float*    zbuf   = (float*)carve(NN * 4);
    (void)ws_size; (void)n_in; (void)in_sizes; (void)out_size;

    // params + weight transposes + deg zeroing + x->bf16, all in one dispatch
    prep_params<<<NF + 2 + HD + ZB + CVB, HD, 0, stream>>>(
        emb, Ws, bs, lw, dW0t, w2lw, b2lw, Wt, deg, x, xb);

    // degrees, CSR build with inline norm + graph bounds in tail blocks
    deg_kernel<<<(NE + 255) / 256, 256, 0, stream>>>(dst, deg, NE);
    chunk_sum_dinv<<<NCH, SCAN_CH, 0, stream>>>(deg, csum, dinv, selfn);
    chunk_apply<<<NCH, SCAN_CH, 0, stream>>>(deg, csum, row_s, cursor);
    csr_fill_gb<<<EB + (NG + 256) / 256, 256, 0, stream>>>(
        src, dst, dinv, cursor, ecol, enorm, batch, gstart);

    // layer 0: aggregate-into-LDS + encoder GEMM + BN stats, one kernel
    enc_fused<<<ENB, 512, 0, stream>>>(
        xb, dW0t, bs, selfn, row_s, ecol, enorm, buf0, part);
    bn_scale<<<HD, 256, 0, stream>>>(part, ENB, gam, bet, scale, shift);

    // layer 1 fully fused: edge-parallel aggregate + GEMM(B-in-VGPR) + stats
    gcn_fused<<<GNB, 512, 0, stream>>>(
        buf0, scale, shift, Wt, bs + HD, selfn, row_s, ecol, enorm, buf1, part);
    bn_scale<<<HD, 256, 0, stream>>>(part, GNB, gam + HD, bet + HD, scale, shift);

    // layer 2 (collapsed): z = relu_bn(conv1)@(W2 lw); fused agg+pool
    bn_dot<<<(NN * 64 + 255) / 256, 256, 0, stream>>>(buf1, scale, shift, w2lw, zbuf);
    pool_fused<<<(NG * 64 + 255) / 256, 256, 0, stream>>>(
        zbuf, selfn, b2lw, row_s, ecol, enorm, gstart, lb, out);
}

// Round 10
// 275.915 us; speedup vs baseline: 1.8726x; 1.8726x over previous
//
#include <hip/hip_runtime.h>
#include <hip/hip_bf16.h>

#define NN 100000      // nodes
#define NE 200000      // edges
#define NF 56          // atom feats
#define HD 256         // hidden
#define NG 2048        // graphs

#define SCAN_CH 512
#define NCH ((NN + SCAN_CH - 1) / SCAN_CH)   // 196 chunks
#define EB ((NE + 255) / 256)                // csr_fill edge blocks

#define ZB 98          // deg-zero blocks in prep_params (25000 int4 / 256)
#define CVB ((NN + 255) / 256)               // x->bf16 convert blocks (391)
#define ENB ((NN + 127) / 128)               // 128-row encoder blocks (782)
#define GNB ((NN + 63) / 64)                 // 64-row fused layer-1 blocks (1563)

typedef __bf16 bf16x8 __attribute__((ext_vector_type(8)));
typedef __bf16 bf16x4 __attribute__((ext_vector_type(4)));
typedef float  floatx4 __attribute__((ext_vector_type(4)));

// ---- param prep (fully merged) ----------------------------------------------
__global__ void prep_params(const float* __restrict__ emb, const float* __restrict__ Ws,
                            const float* __restrict__ bs, const float* __restrict__ lw,
                            __bf16* __restrict__ dW0t,
                            float* __restrict__ w2lw, float* __restrict__ b2lw,
                            __bf16* __restrict__ Wt, unsigned* __restrict__ deg,
                            const int* __restrict__ x, __bf16* __restrict__ xb) {
    __shared__ float row[HD];
    int c = threadIdx.x;
    int f = blockIdx.x;
    if (f >= NF + 2) {
        int g = f - (NF + 2);
        if (g < HD) {       // Wt[n=g][k=c] = Ws[1][c][g]
            Wt[(size_t)g * HD + c] = (__bf16)Ws[(size_t)HD * HD + (size_t)c * HD + g];
        } else if (g < HD + ZB) {   // zero deg as int4
            int idx = (g - HD) * HD + c;
            if (idx < NN / 4) ((int4*)deg)[idx] = make_int4(0, 0, 0, 0);
        } else {            // x -> bf16 pad-64 convert, col 56 = 1
            int r = (g - HD - ZB) * 256 + c;
            if (r < NN) {
                const int* xr = x + (size_t)r * NF;
                __bf16 o[64];
                #pragma unroll
                for (int j = 0; j < 14; ++j) {
                    int4 iv = *(const int4*)&xr[j * 4];
                    o[j * 4 + 0] = (__bf16)(float)iv.x;
                    o[j * 4 + 1] = (__bf16)(float)iv.y;
                    o[j * 4 + 2] = (__bf16)(float)iv.z;
                    o[j * 4 + 3] = (__bf16)(float)iv.w;
                }
                o[56] = (__bf16)1.0f;
                #pragma unroll
                for (int j = 57; j < 64; ++j) o[j] = (__bf16)0.0f;
                #pragma unroll
                for (int j = 0; j < 8; ++j)
                    *(bf16x8*)&xb[(size_t)r * 64 + j * 8] = *(const bf16x8*)&o[j * 8];
            }
        }
        return;
    }
    if (f == NF + 1) {   // layer-2 collapse params
        const float* W2 = Ws + (size_t)2 * HD * HD;
        float acc = 0.f;
        for (int k = 0; k < HD; ++k) acc += W2[(size_t)c * HD + k] * lw[k];
        w2lw[c] = acc;
        row[c] = bs[2 * HD + c] * lw[c];
        __syncthreads();
        for (int off = 128; off > 0; off >>= 1) {
            if (c < off) row[c] += row[c + off];
            __syncthreads();
        }
        if (c == 0) *b2lw = row[0];
        return;
    }
    if (f < NF) {
        row[c] = emb[(f * 2 + 1) * HD + c] - emb[(f * 2 + 0) * HD + c];
    } else {
        float s = 0.f;
        for (int ff = 0; ff < NF; ++ff) s += emb[(ff * 2) * HD + c];
        row[c] = s;
    }
    __syncthreads();
    float acc = 0.f;
    for (int k = 0; k < HD; ++k) acc += row[k] * Ws[k * HD + c];   // W0
    if (f < NF) {
        dW0t[c * 64 + f] = (__bf16)acc;          // transposed bf16, direct
    } else {
        dW0t[c * 64 + 56] = (__bf16)acc;         // base row via rowsum column
        #pragma unroll
        for (int k = 57; k < 64; ++k) dW0t[c * 64 + k] = (__bf16)0.f;
    }
}

// ---- degree ------------------------------------------------------------------
__global__ void deg_kernel(const int* __restrict__ dst, unsigned* __restrict__ deg, int E) {
    int e = blockIdx.x * blockDim.x + threadIdx.x;
    if (e < E) atomicAdd(&deg[dst[e]], 1u);
}

// merged: per-chunk degree sum (for scan) + dinv/selfn
__global__ void chunk_sum_dinv(const unsigned* __restrict__ deg, unsigned* __restrict__ csum,
                               float* __restrict__ dinv, float* __restrict__ selfn) {
    __shared__ unsigned s[SCAN_CH];
    int t = threadIdx.x;
    int base = blockIdx.x * SCAN_CH;
    unsigned v = (base + t < NN) ? deg[base + t] : 0u;
    s[t] = v;
    if (base + t < NN) {
        float d = (float)(v + 1u);   // +1 self loop
        dinv[base + t]  = rsqrtf(d);
        selfn[base + t] = 1.0f / d;
    }
    __syncthreads();
    for (int off = SCAN_CH / 2; off > 0; off >>= 1) {
        if (t < off) s[t] += s[t + off];
        __syncthreads();
    }
    if (t == 0) csum[blockIdx.x] = s[0];
}

// chunk_apply with INLINE scan of csum (each block re-scans 196 chunk sums)
__global__ void chunk_apply(const unsigned* __restrict__ deg, const unsigned* __restrict__ csum,
                            unsigned* __restrict__ row_start, unsigned* __restrict__ cursor) {
    __shared__ unsigned s[SCAN_CH];
    __shared__ unsigned cs[256];
    int t = threadIdx.x;
    if (t < 256) cs[t] = (t < NCH) ? csum[t] : 0u;
    __syncthreads();
    for (int off = 1; off < 256; off <<= 1) {
        unsigned add = (t < 256 && t >= off) ? cs[t - off] : 0u;
        __syncthreads();
        if (t < 256) cs[t] += add;
        __syncthreads();
    }
    unsigned chunk_base = (blockIdx.x == 0) ? 0u : cs[blockIdx.x - 1];

    int base = blockIdx.x * SCAN_CH;
    unsigned v = (base + t < NN) ? deg[base + t] : 0u;
    s[t] = v;
    __syncthreads();
    for (int off = 1; off < SCAN_CH; off <<= 1) {
        unsigned add = (t >= off) ? s[t - off] : 0u;
        __syncthreads();
        s[t] += add;
        __syncthreads();
    }
    if (base + t < NN) {
        unsigned rs = chunk_base + s[t] - v;   // exclusive scan value
        row_start[base + t] = rs;
        cursor[base + t] = rs;
    }
    if (blockIdx.x == 0 && t == 0) row_start[NN] = NE;
}

// csr_fill (inline norm) + graph_bounds merged into the tail blocks
__global__ void csr_fill_gb(const int* __restrict__ src, const int* __restrict__ dst,
                            const float* __restrict__ dinv, unsigned* __restrict__ cursor,
                            int* __restrict__ ecol, float* __restrict__ enorm,
                            const int* __restrict__ batch, unsigned* __restrict__ gstart) {
    int t = threadIdx.x;
    if (blockIdx.x < EB) {
        int e = blockIdx.x * 256 + t;
        if (e < NE) {
            int s = src[e], d = dst[e];
            unsigned pos = atomicAdd(&cursor[d], 1u);
            ecol[pos] = s;
            enorm[pos] = dinv[s] * dinv[d];
        }
    } else {
        int g = (blockIdx.x - EB) * 256 + t;
        if (g <= NG) {
            int lo = 0, hi = NN;
            while (lo < hi) {
                int mid = (lo + hi) >> 1;
                if (batch[mid] < g) lo = mid + 1; else hi = mid;
            }
            gstart[g] = (unsigned)lo;
        }
    }
}

// ---- fused layer-0: aggregate S.xb into LDS A-tile, then GEMM + BN stats ----
#define ELSTR 68
__global__ void __launch_bounds__(512) enc_fused(const __bf16* __restrict__ xb,
                                                 const __bf16* __restrict__ dW0t,
                                                 const float* __restrict__ b0,
                                                 const float* __restrict__ selfn,
                                                 const unsigned* __restrict__ row_start,
                                                 const int* __restrict__ ecol,
                                                 const float* __restrict__ enorm,
                                                 __bf16* __restrict__ C,
                                                 float* __restrict__ part) {
    __shared__ __bf16 sA[128 * ELSTR];   // 17408 B (aggregated A-tile)
    __shared__ __bf16 sB[256 * ELSTR];   // 34816 B
    __shared__ float psum[8][64];        // 2 KB
    __shared__ float psq[8][64];         // 2 KB
    int t = threadIdx.x;
    int m0 = blockIdx.x * 128;
    int lane = t & 63, w = t >> 6;
    int quad = lane >> 4, l16 = lane & 15;
    int mw = (w & 1) * 64, nw = (w >> 1) * 64;

    {   // B stage: 256 rows x 64 cols bf16
        int bn = t >> 1;
        int kh = (t & 1) * 32;
        #pragma unroll
        for (int j = 0; j < 4; ++j)
            *(bf16x8*)&sB[bn * ELSTR + kh + j * 8] =
                *(const bf16x8*)&dW0t[(size_t)bn * 64 + kh + j * 8];
    }
    {   // A stage = in-place aggregation: 4 threads per node, 16 cols each
        int r = t >> 2;
        int p = (t & 3) * 16;
        int n = m0 + r;
        float acc[16];
        #pragma unroll
        for (int i = 0; i < 16; ++i) acc[i] = 0.f;
        if (n < NN) {
            float sn = selfn[n];
            bf16x8 a0 = *(const bf16x8*)&xb[(size_t)n * 64 + p];
            bf16x8 a1 = *(const bf16x8*)&xb[(size_t)n * 64 + p + 8];
            #pragma unroll
            for (int i = 0; i < 8; ++i) {
                acc[i]     = (float)a0[i] * sn;
                acc[8 + i] = (float)a1[i] * sn;
            }
            unsigned e0 = row_start[n], e1 = row_start[n + 1];
            unsigned e = e0;
            for (; e + 2 <= e1; e += 2) {
                int s0 = ecol[e], s1 = ecol[e + 1];
                float n0v = enorm[e], n1v = enorm[e + 1];
                bf16x8 u00 = *(const bf16x8*)&xb[(size_t)s0 * 64 + p];
                bf16x8 u01 = *(const bf16x8*)&xb[(size_t)s0 * 64 + p + 8];
                bf16x8 u10 = *(const bf16x8*)&xb[(size_t)s1 * 64 + p];
                bf16x8 u11 = *(const bf16x8*)&xb[(size_t)s1 * 64 + p + 8];
                #pragma unroll
                for (int i = 0; i < 8; ++i) {
                    acc[i]     += (float)u00[i] * n0v + (float)u10[i] * n1v;
                    acc[8 + i] += (float)u01[i] * n0v + (float)u11[i] * n1v;
                }
            }
            if (e < e1) {
                int s0 = ecol[e];
                float n0v = enorm[e];
                bf16x8 u00 = *(const bf16x8*)&xb[(size_t)s0 * 64 + p];
                bf16x8 u01 = *(const bf16x8*)&xb[(size_t)s0 * 64 + p + 8];
                #pragma unroll
                for (int i = 0; i < 8; ++i) {
                    acc[i]     += (float)u00[i] * n0v;
                    acc[8 + i] += (float)u01[i] * n0v;
                }
            }
        }
        bf16x8 o0, o1;
        #pragma unroll
        for (int i = 0; i < 8; ++i) { o0[i] = (__bf16)acc[i]; o1[i] = (__bf16)acc[8 + i]; }
        *(bf16x8*)&sA[r * ELSTR + p]     = o0;
        *(bf16x8*)&sA[r * ELSTR + p + 8] = o1;
    }
    __syncthreads();

    floatx4 acc[4][4] = {};
    #pragma unroll
    for (int s = 0; s < 2; ++s) {
        bf16x8 af[4], bfr[4];
        #pragma unroll
        for (int i = 0; i < 4; ++i)
            af[i] = *(const bf16x8*)&sA[(mw + i * 16 + l16) * ELSTR + s * 32 + quad * 8];
        #pragma unroll
        for (int i = 0; i < 4; ++i)
            bfr[i] = *(const bf16x8*)&sB[(nw + i * 16 + l16) * ELSTR + s * 32 + quad * 8];
        #pragma unroll
        for (int mi = 0; mi < 4; ++mi)
            #pragma unroll
            for (int ni = 0; ni < 4; ++ni)
                acc[mi][ni] = __builtin_amdgcn_mfma_f32_16x16x32_bf16(
                    af[mi], bfr[ni], acc[mi][ni], 0, 0, 0);
    }

    float bw[4];
    #pragma unroll
    for (int ni = 0; ni < 4; ++ni) bw[ni] = b0[nw + ni * 16 + l16];
    float ls[4] = {0.f, 0.f, 0.f, 0.f};
    float lq[4] = {0.f, 0.f, 0.f, 0.f};
    #pragma unroll
    for (int mi = 0; mi < 4; ++mi) {
        #pragma unroll
        for (int r = 0; r < 4; ++r) {
            int row = m0 + mw + mi * 16 + quad * 4 + r;
            if (row < NN) {
                #pragma unroll
                for (int ni = 0; ni < 4; ++ni) {
                    float v = acc[mi][ni][r] + bw[ni];
                    C[(size_t)row * HD + nw + ni * 16 + l16] = (__bf16)v;
                    ls[ni] += v;
                    lq[ni] += v * v;
                }
            }
        }
    }
    // reduce across quads (rows) -> lanes 0..15 hold per-column partials
    #pragma unroll
    for (int ni = 0; ni < 4; ++ni) {
        ls[ni] += __shfl_xor(ls[ni], 16, 64);
        ls[ni] += __shfl_xor(ls[ni], 32, 64);
        lq[ni] += __shfl_xor(lq[ni], 16, 64);
        lq[ni] += __shfl_xor(lq[ni], 32, 64);
    }
    if (lane < 16) {
        #pragma unroll
        for (int ni = 0; ni < 4; ++ni) {
            psum[w][ni * 16 + l16] = ls[ni];
            psq[w][ni * 16 + l16]  = lq[ni];
        }
    }
    __syncthreads();
    if (!(w & 1) && lane < 16) {   // combine the two mw waves sharing nw
        #pragma unroll
        for (int ni = 0; ni < 4; ++ni) {
            int ci = ni * 16 + l16;
            part[(size_t)blockIdx.x * 512 + nw + ci]       = psum[w][ci] + psum[w + 1][ci];
            part[(size_t)blockIdx.x * 512 + 256 + nw + ci] = psq[w][ci]  + psq[w + 1][ci];
        }
    }
}

// ---- fused layer-1 (R7 phase A + barrier-free register-B phase B) -----------
// Phase A: wave-per-node gather of S.relu_bn(conv0) into swizzled bf16 LDS
// tile (proven R7 path, no atomics). Phase B: each wave's 32-col B-slice lives
// in 64 VGPRs (preloaded before phase A, L2-hot, hides under gather) -> the
// MFMA loop has NO staging and NO barriers. Per-block barriers: 17 -> 1.
__global__ void __launch_bounds__(512) gcn_fused(const __bf16* __restrict__ h0,
                                                 const float* __restrict__ scale,
                                                 const float* __restrict__ shift,
                                                 const __bf16* __restrict__ Wt,
                                                 const float* __restrict__ b1,
                                                 const float* __restrict__ selfn,
                                                 const unsigned* __restrict__ row_start,
                                                 const int* __restrict__ ecol,
                                                 const float* __restrict__ enorm,
                                                 __bf16* __restrict__ C,
                                                 float* __restrict__ part) {
    __shared__ __bf16 sA[64 * 256];    // 32 KB, swizzled
    int t = threadIdx.x;
    int m0 = blockIdx.x * 64;
    int lane = t & 63, w = t >> 6;
    int quad = lane >> 4, l16 = lane & 15;

    // B-slice into registers: wave w owns output cols [w*32, w*32+32), K=256.
    bf16x8 breg[8][2];
    #pragma unroll
    for (int c = 0; c < 8; ++c)
        #pragma unroll
        for (int ni = 0; ni < 2; ++ni)
            breg[c][ni] = *(const bf16x8*)&Wt[(size_t)(w * 32 + ni * 16 + l16) * HD + c * 32 + quad * 8];

    {   // ---- phase A: wave per node, 8 nodes per wave, lane = 4 cols --------
        int c4 = lane * 4;
        float4 sc = *(const float4*)&scale[c4];
        float4 sh = *(const float4*)&shift[c4];
        for (int g = 0; g < 8; ++g) {
            int r = w * 8 + g;
            int n = m0 + r;
            float4 acc = make_float4(0.f, 0.f, 0.f, 0.f);
            if (n < NN) {
                float sn = selfn[n];
                bf16x4 hv = *(const bf16x4*)&h0[(size_t)n * HD + c4];
                acc.x = fmaxf((float)hv[0] * sc.x + sh.x, 0.f) * sn;
                acc.y = fmaxf((float)hv[1] * sc.y + sh.y, 0.f) * sn;
                acc.z = fmaxf((float)hv[2] * sc.z + sh.z, 0.f) * sn;
                acc.w = fmaxf((float)hv[3] * sc.w + sh.w, 0.f) * sn;
                unsigned e = row_start[n], e1 = row_start[n + 1];
                for (; e + 2 <= e1; e += 2) {
                    int s0 = ecol[e], s1 = ecol[e + 1];
                    float n0 = enorm[e], n1 = enorm[e + 1];
                    bf16x4 u0 = *(const bf16x4*)&h0[(size_t)s0 * HD + c4];
                    bf16x4 u1 = *(const bf16x4*)&h0[(size_t)s1 * HD + c4];
                    acc.x += fmaxf((float)u0[0] * sc.x + sh.x, 0.f) * n0
                           + fmaxf((float)u1[0] * sc.x + sh.x, 0.f) * n1;
                    acc.y += fmaxf((float)u0[1] * sc.y + sh.y, 0.f) * n0
                           + fmaxf((float)u1[1] * sc.y + sh.y, 0.f) * n1;
                    acc.z += fmaxf((float)u0[2] * sc.z + sh.z, 0.f) * n0
                           + fmaxf((float)u1[2] * sc.z + sh.z, 0.f) * n1;
                    acc.w += fmaxf((float)u0[3] * sc.w + sh.w, 0.f) * n0
                           + fmaxf((float)u1[3] * sc.w + sh.w, 0.f) * n1;
                }
                if (e < e1) {
                    int s0 = ecol[e];
                    float n0 = enorm[e];
                    bf16x4 u0 = *(const bf16x4*)&h0[(size_t)s0 * HD + c4];
                    acc.x += fmaxf((float)u0[0] * sc.x + sh.x, 0.f) * n0;
                    acc.y += fmaxf((float)u0[1] * sc.y + sh.y, 0.f) * n0;
                    acc.z += fmaxf((float)u0[2] * sc.z + sh.z, 0.f) * n0;
                    acc.w += fmaxf((float)u0[3] * sc.w + sh.w, 0.f) * n0;
                }
            }
            bf16x4 o;
            o[0] = (__bf16)acc.x; o[1] = (__bf16)acc.y;
            o[2] = (__bf16)acc.z; o[3] = (__bf16)acc.w;
            // swizzled store: granule (16B) = lane>>1, swz = gran ^ (r&7)
            int swz = ((lane >> 1) ^ (r & 7));
            *(bf16x4*)&sA[r * 256 + swz * 8 + (lane & 1) * 4] = o;
        }
    }
    __syncthreads();

    // ---- phase B: K=256 GEMM, B from VGPRs, zero barriers --------------------
    floatx4 cacc[4][2] = {};
    #pragma unroll
    for (int c = 0; c < 8; ++c) {
        bf16x8 af[4];
        #pragma unroll
        for (int mi = 0; mi < 4; ++mi) {
            int row = mi * 16 + l16;
            int g = (c * 4 + quad) ^ (l16 & 7);
            af[mi] = *(const bf16x8*)&sA[row * 256 + (g << 3)];
        }
        #pragma unroll
        for (int mi = 0; mi < 4; ++mi)
            #pragma unroll
            for (int ni = 0; ni < 2; ++ni)
                cacc[mi][ni] = __builtin_amdgcn_mfma_f32_16x16x32_bf16(
                    af[mi], breg[c][ni], cacc[mi][ni], 0, 0, 0);
    }

    // ---- epilogue: bias, C-write, per-column BN partials ---------------------
    float bw[2];
    #pragma unroll
    for (int ni = 0; ni < 2; ++ni) bw[ni] = b1[w * 32 + ni * 16 + l16];
    float ls[2] = {0.f, 0.f}, lq[2] = {0.f, 0.f};
    #pragma unroll
    for (int mi = 0; mi < 4; ++mi) {
        #pragma unroll
        for (int r_ = 0; r_ < 4; ++r_) {
            int row = m0 + mi * 16 + quad * 4 + r_;
            if (row < NN) {
                #pragma unroll
                for (int ni = 0; ni < 2; ++ni) {
                    float v = cacc[mi][ni][r_] + bw[ni];
                    C[(size_t)row * HD + w * 32 + ni * 16 + l16] = (__bf16)v;
                    ls[ni] += v;
                    lq[ni] += v * v;
                }
            }
        }
    }
    #pragma unroll
    for (int ni = 0; ni < 2; ++ni) {
        ls[ni] += __shfl_xor(ls[ni], 16, 64);
        ls[ni] += __shfl_xor(ls[ni], 32, 64);
        lq[ni] += __shfl_xor(lq[ni], 16, 64);
        lq[ni] += __shfl_xor(lq[ni], 32, 64);
    }
    if (lane < 16) {
        #pragma unroll
        for (int ni = 0; ni < 2; ++ni) {
            int ci = w * 32 + ni * 16 + l16;
            part[(size_t)blockIdx.x * 512 + ci]       = ls[ni];
            part[(size_t)blockIdx.x * 512 + 256 + ci] = lq[ni];
        }
    }
}

// Stage 2: one block per column c; reduce nb per-block partials, emit scale/shift.
__global__ void __launch_bounds__(256) bn_scale(const float* __restrict__ part, int nb,
                                                const float* __restrict__ gamma,
                                                const float* __restrict__ beta,
                                                float* __restrict__ scale,
                                                float* __restrict__ shift) {
    __shared__ float rs[256], rq[256];
    int t = threadIdx.x;
    int c = blockIdx.x;
    float s = 0.f, q = 0.f;
    for (int j = t; j < nb; j += 256) {
        s += part[(size_t)j * 512 + c];
        q += part[(size_t)j * 512 + 256 + c];
    }
    rs[t] = s; rq[t] = q;
    __syncthreads();
    for (int off = 128; off > 0; off >>= 1) {
        if (t < off) { rs[t] += rs[t + off]; rq[t] += rq[t + off]; }
        __syncthreads();
    }
    if (t == 0) {
        const float inv_n = 1.0f / (float)NN;
        float mu  = rs[0] * inv_n;
        float var = rq[0] * inv_n - mu * mu;
        float rstd = rsqrtf(var + 1e-5f);
        float sc = gamma[c] * rstd;
        scale[c] = sc;
        shift[c] = beta[c] - mu * sc;
    }
}

// ---- layer-2 collapse: z[n] = relu_bn(h[n]) . w2lw  (one wave per node) -----
__global__ void __launch_bounds__(256) bn_dot(const __bf16* __restrict__ h,
                                              const float* __restrict__ scale,
                                              const float* __restrict__ shift,
                                              const float* __restrict__ w2lw,
                                              float* __restrict__ z) {
    int tid = blockIdx.x * 256 + threadIdx.x;
    int n = tid >> 6;
    if (n >= NN) return;
    int l = tid & 63;
    int c4 = l * 4;
    bf16x4 a = *(const bf16x4*)&h[(size_t)n * HD + c4];
    float4 sc = *(const float4*)&scale[c4];
    float4 sh = *(const float4*)&shift[c4];
    float4 wv = *(const float4*)&w2lw[c4];
    float d = fmaxf((float)a[0] * sc.x + sh.x, 0.f) * wv.x
            + fmaxf((float)a[1] * sc.y + sh.y, 0.f) * wv.y
            + fmaxf((float)a[2] * sc.z + sh.z, 0.f) * wv.z
            + fmaxf((float)a[3] * sc.w + sh.w, 0.f) * wv.w;
    #pragma unroll
    for (int off = 32; off > 0; off >>= 1) d += __shfl_down(d, off, 64);
    if (l == 0) z[n] = d;
}

// ---- fused final: per-graph wave; lanes stride nodes; scalar edge loop ------
__global__ void __launch_bounds__(256) pool_fused(const float* __restrict__ z,
                                                  const float* __restrict__ selfn,
                                                  const float* __restrict__ b2lw,
                                                  const unsigned* __restrict__ row_start,
                                                  const int* __restrict__ ecol,
                                                  const float* __restrict__ enorm,
                                                  const unsigned* __restrict__ gstart,
                                                  const float* __restrict__ lb,
                                                  float* __restrict__ out) {
    int tid = blockIdx.x * 256 + threadIdx.x;
    int g = tid >> 6;
    if (g >= NG) return;
    int l = tid & 63;
    unsigned s0 = gstart[g], s1 = gstart[g + 1];
    float bb = *b2lw;
    float s = 0.f;
    for (unsigned i = s0 + l; i < s1; i += 64) {
        float d = selfn[i] * z[i] + bb;
        unsigned e0 = row_start[i], e1 = row_start[i + 1];
        for (unsigned e = e0; e < e1; ++e)
            d += enorm[e] * z[ecol[e]];
        s += d;
    }
    #pragma unroll
    for (int off = 32; off > 0; off >>= 1) s += __shfl_down(s, off, 64);
    if (l == 0) out[g] = s / fmaxf((float)(s1 - s0), 1.0f) + lb[0];
}

// ---- driver -----------------------------------------------------------------
extern "C" void kernel_launch(void* const* d_in, const int* in_sizes, int n_in,
                              void* d_out, int out_size, void* d_ws, size_t ws_size,
                              hipStream_t stream) {
    const int*   x     = (const int*)d_in[0];
    const int*   ei    = (const int*)d_in[1];
    const int*   batch = (const int*)d_in[2];
    const float* emb   = (const float*)d_in[3];
    const float* Ws    = (const float*)d_in[4];
    const float* bs    = (const float*)d_in[5];
    const float* gam   = (const float*)d_in[6];
    const float* bet   = (const float*)d_in[7];
    const float* lw    = (const float*)d_in[8];
    const float* lb    = (const float*)d_in[9];
    float* out = (float*)d_out;

    const int* src = ei;
    const int* dst = ei + NE;

    // workspace carve-up (256-B aligned)
    char* p = (char*)d_ws;
    size_t off = 0;
    auto carve = [&](size_t bytes) { void* r = p + off; off = (off + bytes + 255) & ~(size_t)255; return r; };
    __bf16*   buf0   = (__bf16*)carve((size_t)NN * HD * 2);   // conv0 (bf16)
    __bf16*   buf1   = (__bf16*)carve((size_t)NN * HD * 2);   // conv1 (bf16)
    __bf16*   xb     = (__bf16*)carve((size_t)NN * 64 * 2);   // x as bf16, pad 64
    __bf16*   dW0t   = (__bf16*)carve(HD * 64 * 2);
    __bf16*   Wt     = (__bf16*)carve((size_t)HD * HD * 2);   // layer-1 only
    float*    w2lw   = (float*)carve(HD * 4);
    float*    b2lw   = (float*)carve(256);
    unsigned* deg    = (unsigned*)carve(NN * 4);
    float*    dinv   = (float*)carve(NN * 4);
    float*    selfn  = (float*)carve(NN * 4);
    unsigned* csum   = (unsigned*)carve(256 * 4);
    unsigned* row_s  = (unsigned*)carve((NN + 1) * 4);
    unsigned* cursor = (unsigned*)carve(NN * 4);
    int*      ecol   = (int*)carve(NE * 4);
    float*    enorm  = (float*)carve(NE * 4);
    float*    part   = (float*)carve((size_t)GNB * 512 * 4);  // 3.2 MB, [blk][512]
    float*    scale  = (float*)carve(HD * 4);
    float*    shift  = (float*)carve(HD * 4);
    unsigned* gstart = (unsigned*)carve((NG + 1) * 4);
    float*    zbuf   = (float*)carve(NN * 4);
    (void)ws_size; (void)n_in; (void)in_sizes; (void)out_size;

    // params + weight transposes + deg zeroing + x->bf16, all in one dispatch
    prep_params<<<NF + 2 + HD + ZB + CVB, HD, 0, stream>>>(
        emb, Ws, bs, lw, dW0t, w2lw, b2lw, Wt, deg, x, xb);

    // degrees, CSR build with inline norm + graph bounds in tail blocks
    deg_kernel<<<(NE + 255) / 256, 256, 0, stream>>>(dst, deg, NE);
    chunk_sum_dinv<<<NCH, SCAN_CH, 0, stream>>>(deg, csum, dinv, selfn);
    chunk_apply<<<NCH, SCAN_CH, 0, stream>>>(deg, csum, row_s, cursor);
    csr_fill_gb<<<EB + (NG + 256) / 256, 256, 0, stream>>>(
        src, dst, dinv, cursor, ecol, enorm, batch, gstart);

    // layer 0: aggregate-into-LDS + encoder GEMM + BN stats, one kernel
    enc_fused<<<ENB, 512, 0, stream>>>(
        xb, dW0t, bs, selfn, row_s, ecol, enorm, buf0, part);
    bn_scale<<<HD, 256, 0, stream>>>(part, ENB, gam, bet, scale, shift);

    // layer 1 fully fused: gather-aggregate into LDS + GEMM(B-in-VGPR) + stats
    gcn_fused<<<GNB, 512, 0, stream>>>(
        buf0, scale, shift, Wt, bs + HD, selfn, row_s, ecol, enorm, buf1, part);
    bn_scale<<<HD, 256, 0, stream>>>(part, GNB, gam + HD, bet + HD, scale, shift);

    // layer 2 (collapsed): z = relu_bn(conv1)@(W2 lw); fused agg+pool
    bn_dot<<<(NN * 64 + 255) / 256, 256, 0, stream>>>(buf1, scale, shift, w2lw, zbuf);
    pool_fused<<<(NG * 64 + 255) / 256, 256, 0, stream>>>(
        zbuf, selfn, b2lw, row_s, ecol, enorm, gstart, lb, out);
}

// Round 11
// 248.932 us; speedup vs baseline: 2.0755x; 1.1084x over previous
//
#include <hip/hip_runtime.h>
#include <hip/hip_bf16.h>

#define NN 100000      // nodes
#define NE 200000      // edges
#define NF 56          // atom feats
#define HD 256         // hidden
#define NG 2048        // graphs

#define SCAN_CH 512
#define NCH ((NN + SCAN_CH - 1) / SCAN_CH)   // 196 chunks
#define EB ((NE + 255) / 256)                // csr_fill edge blocks

#define ZB 98          // deg-zero blocks in prep_params (25000 int4 / 256)
#define CVB ((NN + 255) / 256)               // x->bf16 convert blocks (391)
#define ENB ((NN + 127) / 128)               // 128-row encoder blocks (782)
#define GNB ((NN + 63) / 64)                 // 64-row fused layer-1 blocks (1563)

typedef __bf16 bf16x8 __attribute__((ext_vector_type(8)));
typedef __bf16 bf16x4 __attribute__((ext_vector_type(4)));
typedef float  floatx4 __attribute__((ext_vector_type(4)));

// ---- param prep (fully merged) ----------------------------------------------
__global__ void prep_params(const float* __restrict__ emb, const float* __restrict__ Ws,
                            const float* __restrict__ bs, const float* __restrict__ lw,
                            __bf16* __restrict__ dW0t,
                            float* __restrict__ w2lw, float* __restrict__ b2lw,
                            __bf16* __restrict__ Wt, unsigned* __restrict__ deg,
                            const int* __restrict__ x, __bf16* __restrict__ xb) {
    __shared__ float row[HD];
    int c = threadIdx.x;
    int f = blockIdx.x;
    if (f >= NF + 2) {
        int g = f - (NF + 2);
        if (g < HD) {       // Wt[n=g][k=c] = Ws[1][c][g]
            Wt[(size_t)g * HD + c] = (__bf16)Ws[(size_t)HD * HD + (size_t)c * HD + g];
        } else if (g < HD + ZB) {   // zero deg as int4
            int idx = (g - HD) * HD + c;
            if (idx < NN / 4) ((int4*)deg)[idx] = make_int4(0, 0, 0, 0);
        } else {            // x -> bf16 pad-64 convert, col 56 = 1
            int r = (g - HD - ZB) * 256 + c;
            if (r < NN) {
                const int* xr = x + (size_t)r * NF;
                __bf16 o[64];
                #pragma unroll
                for (int j = 0; j < 14; ++j) {
                    int4 iv = *(const int4*)&xr[j * 4];
                    o[j * 4 + 0] = (__bf16)(float)iv.x;
                    o[j * 4 + 1] = (__bf16)(float)iv.y;
                    o[j * 4 + 2] = (__bf16)(float)iv.z;
                    o[j * 4 + 3] = (__bf16)(float)iv.w;
                }
                o[56] = (__bf16)1.0f;
                #pragma unroll
                for (int j = 57; j < 64; ++j) o[j] = (__bf16)0.0f;
                #pragma unroll
                for (int j = 0; j < 8; ++j)
                    *(bf16x8*)&xb[(size_t)r * 64 + j * 8] = *(const bf16x8*)&o[j * 8];
            }
        }
        return;
    }
    if (f == NF + 1) {   // layer-2 collapse params
        const float* W2 = Ws + (size_t)2 * HD * HD;
        float acc = 0.f;
        for (int k = 0; k < HD; ++k) acc += W2[(size_t)c * HD + k] * lw[k];
        w2lw[c] = acc;
        row[c] = bs[2 * HD + c] * lw[c];
        __syncthreads();
        for (int off = 128; off > 0; off >>= 1) {
            if (c < off) row[c] += row[c + off];
            __syncthreads();
        }
        if (c == 0) *b2lw = row[0];
        return;
    }
    if (f < NF) {
        row[c] = emb[(f * 2 + 1) * HD + c] - emb[(f * 2 + 0) * HD + c];
    } else {
        float s = 0.f;
        for (int ff = 0; ff < NF; ++ff) s += emb[(ff * 2) * HD + c];
        row[c] = s;
    }
    __syncthreads();
    float acc = 0.f;
    for (int k = 0; k < HD; ++k) acc += row[k] * Ws[k * HD + c];   // W0
    if (f < NF) {
        dW0t[c * 64 + f] = (__bf16)acc;          // transposed bf16, direct
    } else {
        dW0t[c * 64 + 56] = (__bf16)acc;         // base row via rowsum column
        #pragma unroll
        for (int k = 57; k < 64; ++k) dW0t[c * 64 + k] = (__bf16)0.f;
    }
}

// ---- degree ------------------------------------------------------------------
__global__ void deg_kernel(const int* __restrict__ dst, unsigned* __restrict__ deg, int E) {
    int e = blockIdx.x * blockDim.x + threadIdx.x;
    if (e < E) atomicAdd(&deg[dst[e]], 1u);
}

// merged: per-chunk degree sum (for scan) + dinv/selfn
__global__ void chunk_sum_dinv(const unsigned* __restrict__ deg, unsigned* __restrict__ csum,
                               float* __restrict__ dinv, float* __restrict__ selfn) {
    __shared__ unsigned s[SCAN_CH];
    int t = threadIdx.x;
    int base = blockIdx.x * SCAN_CH;
    unsigned v = (base + t < NN) ? deg[base + t] : 0u;
    s[t] = v;
    if (base + t < NN) {
        float d = (float)(v + 1u);   // +1 self loop
        dinv[base + t]  = rsqrtf(d);
        selfn[base + t] = 1.0f / d;
    }
    __syncthreads();
    for (int off = SCAN_CH / 2; off > 0; off >>= 1) {
        if (t < off) s[t] += s[t + off];
        __syncthreads();
    }
    if (t == 0) csum[blockIdx.x] = s[0];
}

// chunk_apply with INLINE scan of csum (each block re-scans 196 chunk sums)
__global__ void chunk_apply(const unsigned* __restrict__ deg, const unsigned* __restrict__ csum,
                            unsigned* __restrict__ row_start, unsigned* __restrict__ cursor) {
    __shared__ unsigned s[SCAN_CH];
    __shared__ unsigned cs[256];
    int t = threadIdx.x;
    if (t < 256) cs[t] = (t < NCH) ? csum[t] : 0u;
    __syncthreads();
    for (int off = 1; off < 256; off <<= 1) {
        unsigned add = (t < 256 && t >= off) ? cs[t - off] : 0u;
        __syncthreads();
        if (t < 256) cs[t] += add;
        __syncthreads();
    }
    unsigned chunk_base = (blockIdx.x == 0) ? 0u : cs[blockIdx.x - 1];

    int base = blockIdx.x * SCAN_CH;
    unsigned v = (base + t < NN) ? deg[base + t] : 0u;
    s[t] = v;
    __syncthreads();
    for (int off = 1; off < SCAN_CH; off <<= 1) {
        unsigned add = (t >= off) ? s[t - off] : 0u;
        __syncthreads();
        s[t] += add;
        __syncthreads();
    }
    if (base + t < NN) {
        unsigned rs = chunk_base + s[t] - v;   // exclusive scan value
        row_start[base + t] = rs;
        cursor[base + t] = rs;
    }
    if (blockIdx.x == 0 && t == 0) row_start[NN] = NE;
}

// csr_fill (inline norm) + graph_bounds merged into the tail blocks
__global__ void csr_fill_gb(const int* __restrict__ src, const int* __restrict__ dst,
                            const float* __restrict__ dinv, unsigned* __restrict__ cursor,
                            int* __restrict__ ecol, float* __restrict__ enorm,
                            const int* __restrict__ batch, unsigned* __restrict__ gstart) {
    int t = threadIdx.x;
    if (blockIdx.x < EB) {
        int e = blockIdx.x * 256 + t;
        if (e < NE) {
            int s = src[e], d = dst[e];
            unsigned pos = atomicAdd(&cursor[d], 1u);
            ecol[pos] = s;
            enorm[pos] = dinv[s] * dinv[d];
        }
    } else {
        int g = (blockIdx.x - EB) * 256 + t;
        if (g <= NG) {
            int lo = 0, hi = NN;
            while (lo < hi) {
                int mid = (lo + hi) >> 1;
                if (batch[mid] < g) lo = mid + 1; else hi = mid;
            }
            gstart[g] = (unsigned)lo;
        }
    }
}

// ---- fused layer-0: aggregate S.xb into LDS A-tile, then GEMM + BN stats ----
#define ELSTR 68
__global__ void __launch_bounds__(512) enc_fused(const __bf16* __restrict__ xb,
                                                 const __bf16* __restrict__ dW0t,
                                                 const float* __restrict__ b0,
                                                 const float* __restrict__ selfn,
                                                 const unsigned* __restrict__ row_start,
                                                 const int* __restrict__ ecol,
                                                 const float* __restrict__ enorm,
                                                 __bf16* __restrict__ C,
                                                 float* __restrict__ part) {
    __shared__ __bf16 sA[128 * ELSTR];   // 17408 B (aggregated A-tile)
    __shared__ __bf16 sB[256 * ELSTR];   // 34816 B
    __shared__ float psum[8][64];        // 2 KB
    __shared__ float psq[8][64];         // 2 KB
    int t = threadIdx.x;
    int m0 = blockIdx.x * 128;
    int lane = t & 63, w = t >> 6;
    int quad = lane >> 4, l16 = lane & 15;
    int mw = (w & 1) * 64, nw = (w >> 1) * 64;

    {   // B stage: 256 rows x 64 cols bf16
        int bn = t >> 1;
        int kh = (t & 1) * 32;
        #pragma unroll
        for (int j = 0; j < 4; ++j)
            *(bf16x8*)&sB[bn * ELSTR + kh + j * 8] =
                *(const bf16x8*)&dW0t[(size_t)bn * 64 + kh + j * 8];
    }
    {   // A stage = in-place aggregation: 4 threads per node, 16 cols each
        int r = t >> 2;
        int p = (t & 3) * 16;
        int n = m0 + r;
        float acc[16];
        #pragma unroll
        for (int i = 0; i < 16; ++i) acc[i] = 0.f;
        if (n < NN) {
            float sn = selfn[n];
            bf16x8 a0 = *(const bf16x8*)&xb[(size_t)n * 64 + p];
            bf16x8 a1 = *(const bf16x8*)&xb[(size_t)n * 64 + p + 8];
            #pragma unroll
            for (int i = 0; i < 8; ++i) {
                acc[i]     = (float)a0[i] * sn;
                acc[8 + i] = (float)a1[i] * sn;
            }
            unsigned e0 = row_start[n], e1 = row_start[n + 1];
            unsigned e = e0;
            for (; e + 2 <= e1; e += 2) {
                int s0 = ecol[e], s1 = ecol[e + 1];
                float n0v = enorm[e], n1v = enorm[e + 1];
                bf16x8 u00 = *(const bf16x8*)&xb[(size_t)s0 * 64 + p];
                bf16x8 u01 = *(const bf16x8*)&xb[(size_t)s0 * 64 + p + 8];
                bf16x8 u10 = *(const bf16x8*)&xb[(size_t)s1 * 64 + p];
                bf16x8 u11 = *(const bf16x8*)&xb[(size_t)s1 * 64 + p + 8];
                #pragma unroll
                for (int i = 0; i < 8; ++i) {
                    acc[i]     += (float)u00[i] * n0v + (float)u10[i] * n1v;
                    acc[8 + i] += (float)u01[i] * n0v + (float)u11[i] * n1v;
                }
            }
            if (e < e1) {
                int s0 = ecol[e];
                float n0v = enorm[e];
                bf16x8 u00 = *(const bf16x8*)&xb[(size_t)s0 * 64 + p];
                bf16x8 u01 = *(const bf16x8*)&xb[(size_t)s0 * 64 + p + 8];
                #pragma unroll
                for (int i = 0; i < 8; ++i) {
                    acc[i]     += (float)u00[i] * n0v;
                    acc[8 + i] += (float)u01[i] * n0v;
                }
            }
        }
        bf16x8 o0, o1;
        #pragma unroll
        for (int i = 0; i < 8; ++i) { o0[i] = (__bf16)acc[i]; o1[i] = (__bf16)acc[8 + i]; }
        *(bf16x8*)&sA[r * ELSTR + p]     = o0;
        *(bf16x8*)&sA[r * ELSTR + p + 8] = o1;
    }
    __syncthreads();

    floatx4 acc[4][4] = {};
    #pragma unroll
    for (int s = 0; s < 2; ++s) {
        bf16x8 af[4], bfr[4];
        #pragma unroll
        for (int i = 0; i < 4; ++i)
            af[i] = *(const bf16x8*)&sA[(mw + i * 16 + l16) * ELSTR + s * 32 + quad * 8];
        #pragma unroll
        for (int i = 0; i < 4; ++i)
            bfr[i] = *(const bf16x8*)&sB[(nw + i * 16 + l16) * ELSTR + s * 32 + quad * 8];
        #pragma unroll
        for (int mi = 0; mi < 4; ++mi)
            #pragma unroll
            for (int ni = 0; ni < 4; ++ni)
                acc[mi][ni] = __builtin_amdgcn_mfma_f32_16x16x32_bf16(
                    af[mi], bfr[ni], acc[mi][ni], 0, 0, 0);
    }

    float bw[4];
    #pragma unroll
    for (int ni = 0; ni < 4; ++ni) bw[ni] = b0[nw + ni * 16 + l16];
    float ls[4] = {0.f, 0.f, 0.f, 0.f};
    float lq[4] = {0.f, 0.f, 0.f, 0.f};
    #pragma unroll
    for (int mi = 0; mi < 4; ++mi) {
        #pragma unroll
        for (int r = 0; r < 4; ++r) {
            int row = m0 + mw + mi * 16 + quad * 4 + r;
            if (row < NN) {
                #pragma unroll
                for (int ni = 0; ni < 4; ++ni) {
                    float v = acc[mi][ni][r] + bw[ni];
                    C[(size_t)row * HD + nw + ni * 16 + l16] = (__bf16)v;
                    ls[ni] += v;
                    lq[ni] += v * v;
                }
            }
        }
    }
    // reduce across quads (rows) -> lanes 0..15 hold per-column partials
    #pragma unroll
    for (int ni = 0; ni < 4; ++ni) {
        ls[ni] += __shfl_xor(ls[ni], 16, 64);
        ls[ni] += __shfl_xor(ls[ni], 32, 64);
        lq[ni] += __shfl_xor(lq[ni], 16, 64);
        lq[ni] += __shfl_xor(lq[ni], 32, 64);
    }
    if (lane < 16) {
        #pragma unroll
        for (int ni = 0; ni < 4; ++ni) {
            psum[w][ni * 16 + l16] = ls[ni];
            psq[w][ni * 16 + l16]  = lq[ni];
        }
    }
    __syncthreads();
    if (!(w & 1) && lane < 16) {   // combine the two mw waves sharing nw
        #pragma unroll
        for (int ni = 0; ni < 4; ++ni) {
            int ci = ni * 16 + l16;
            part[(size_t)blockIdx.x * 512 + nw + ci]       = psum[w][ci] + psum[w + 1][ci];
            part[(size_t)blockIdx.x * 512 + 256 + nw + ci] = psq[w][ci]  + psq[w + 1][ci];
        }
    }
}

// ---- fused layer-1: conv1 = (S . relu_bn(conv0)) @ W1 + b1, + BN stats ------
// M-tile 64, 512 thr / 8 waves. Phase A: wave-per-node (8 nodes/wave) aggregates
// S.relu_bn(conv0) into a granule-XOR-swizzled LDS A-tile. Phase B: K=256 GEMM,
// B streamed in 32-K chunks with register prefetch. Wave w owns output cols
// [w*32, w*32+32) -> per-column BN stats need no LDS. (Empirical optimum of 5
// structural variants: R5 split, R7 this, R8 M=32, R9 edge-atomics, R10 reg-B.)
__global__ void __launch_bounds__(512) gcn_fused(const __bf16* __restrict__ h0,
                                                 const float* __restrict__ scale,
                                                 const float* __restrict__ shift,
                                                 const __bf16* __restrict__ Wt,
                                                 const float* __restrict__ b1,
                                                 const float* __restrict__ selfn,
                                                 const unsigned* __restrict__ row_start,
                                                 const int* __restrict__ ecol,
                                                 const float* __restrict__ enorm,
                                                 __bf16* __restrict__ C,
                                                 float* __restrict__ part) {
    __shared__ __bf16 sA[64 * 256];    // 32 KB, swizzled
    __shared__ __bf16 sB[256 * 36];    // 18 KB (32-K chunk, LSTR pad)
    int t = threadIdx.x;
    int m0 = blockIdx.x * 64;
    int lane = t & 63, w = t >> 6;
    int quad = lane >> 4, l16 = lane & 15;

    // B chunk-0 register prefetch (overlaps with phase A)
    int bn = t >> 1, bk = (t & 1) * 16;
    bf16x8 pb[2];
    #pragma unroll
    for (int j = 0; j < 2; ++j)
        pb[j] = *(const bf16x8*)&Wt[(size_t)bn * HD + bk + j * 8];

    {   // ---- phase A: wave per node, 8 nodes per wave, lane = 4 cols --------
        int c4 = lane * 4;
        float4 sc = *(const float4*)&scale[c4];
        float4 sh = *(const float4*)&shift[c4];
        for (int g = 0; g < 8; ++g) {
            int r = w * 8 + g;
            int n = m0 + r;
            float4 acc = make_float4(0.f, 0.f, 0.f, 0.f);
            if (n < NN) {
                float sn = selfn[n];
                bf16x4 hv = *(const bf16x4*)&h0[(size_t)n * HD + c4];
                acc.x = fmaxf((float)hv[0] * sc.x + sh.x, 0.f) * sn;
                acc.y = fmaxf((float)hv[1] * sc.y + sh.y, 0.f) * sn;
                acc.z = fmaxf((float)hv[2] * sc.z + sh.z, 0.f) * sn;
                acc.w = fmaxf((float)hv[3] * sc.w + sh.w, 0.f) * sn;
                unsigned e = row_start[n], e1 = row_start[n + 1];
                for (; e + 2 <= e1; e += 2) {
                    int s0 = ecol[e], s1 = ecol[e + 1];
                    float n0 = enorm[e], n1 = enorm[e + 1];
                    bf16x4 u0 = *(const bf16x4*)&h0[(size_t)s0 * HD + c4];
                    bf16x4 u1 = *(const bf16x4*)&h0[(size_t)s1 * HD + c4];
                    acc.x += fmaxf((float)u0[0] * sc.x + sh.x, 0.f) * n0
                           + fmaxf((float)u1[0] * sc.x + sh.x, 0.f) * n1;
                    acc.y += fmaxf((float)u0[1] * sc.y + sh.y, 0.f) * n0
                           + fmaxf((float)u1[1] * sc.y + sh.y, 0.f) * n1;
                    acc.z += fmaxf((float)u0[2] * sc.z + sh.z, 0.f) * n0
                           + fmaxf((float)u1[2] * sc.z + sh.z, 0.f) * n1;
                    acc.w += fmaxf((float)u0[3] * sc.w + sh.w, 0.f) * n0
                           + fmaxf((float)u1[3] * sc.w + sh.w, 0.f) * n1;
                }
                if (e < e1) {
                    int s0 = ecol[e];
                    float n0 = enorm[e];
                    bf16x4 u0 = *(const bf16x4*)&h0[(size_t)s0 * HD + c4];
                    acc.x += fmaxf((float)u0[0] * sc.x + sh.x, 0.f) * n0;
                    acc.y += fmaxf((float)u0[1] * sc.y + sh.y, 0.f) * n0;
                    acc.z += fmaxf((float)u0[2] * sc.z + sh.z, 0.f) * n0;
                    acc.w += fmaxf((float)u0[3] * sc.w + sh.w, 0.f) * n0;
                }
            }
            bf16x4 o;
            o[0] = (__bf16)acc.x; o[1] = (__bf16)acc.y;
            o[2] = (__bf16)acc.z; o[3] = (__bf16)acc.w;
            // swizzled store: granule (16B) = lane>>1, swz = gran ^ (r&7)
            int swz = ((lane >> 1) ^ (r & 7));
            *(bf16x4*)&sA[r * 256 + swz * 8 + (lane & 1) * 4] = o;
        }
    }

    // ---- phase B: K-256 GEMM, 8 chunks of 32 ---------------------------------
    floatx4 cacc[4][2] = {};
    for (int k0 = 0; k0 < 256; k0 += 32) {
        *(bf16x8*)&sB[bn * 36 + bk]     = pb[0];
        *(bf16x8*)&sB[bn * 36 + bk + 8] = pb[1];
        __syncthreads();

        if (k0 + 32 < 256) {
            #pragma unroll
            for (int j = 0; j < 2; ++j)
                pb[j] = *(const bf16x8*)&Wt[(size_t)bn * HD + k0 + 32 + bk + j * 8];
        }

        bf16x8 af[4], bfr[2];
        int gbase = (k0 >> 3) + quad;
        #pragma unroll
        for (int mi = 0; mi < 4; ++mi) {
            int row = mi * 16 + l16;
            af[mi] = *(const bf16x8*)&sA[row * 256 + ((gbase ^ (l16 & 7)) << 3)];
        }
        #pragma unroll
        for (int ni = 0; ni < 2; ++ni)
            bfr[ni] = *(const bf16x8*)&sB[(w * 32 + ni * 16 + l16) * 36 + quad * 8];
        #pragma unroll
        for (int mi = 0; mi < 4; ++mi)
            #pragma unroll
            for (int ni = 0; ni < 2; ++ni)
                cacc[mi][ni] = __builtin_amdgcn_mfma_f32_16x16x32_bf16(
                    af[mi], bfr[ni], cacc[mi][ni], 0, 0, 0);
        __syncthreads();
    }

    // ---- epilogue: bias, C-write, per-column BN partials ---------------------
    float bw[2];
    #pragma unroll
    for (int ni = 0; ni < 2; ++ni) bw[ni] = b1[w * 32 + ni * 16 + l16];
    float ls[2] = {0.f, 0.f}, lq[2] = {0.f, 0.f};
    #pragma unroll
    for (int mi = 0; mi < 4; ++mi) {
        #pragma unroll
        for (int r_ = 0; r_ < 4; ++r_) {
            int row = m0 + mi * 16 + quad * 4 + r_;
            if (row < NN) {
                #pragma unroll
                for (int ni = 0; ni < 2; ++ni) {
                    float v = cacc[mi][ni][r_] + bw[ni];
                    C[(size_t)row * HD + w * 32 + ni * 16 + l16] = (__bf16)v;
                    ls[ni] += v;
                    lq[ni] += v * v;
                }
            }
        }
    }
    #pragma unroll
    for (int ni = 0; ni < 2; ++ni) {
        ls[ni] += __shfl_xor(ls[ni], 16, 64);
        ls[ni] += __shfl_xor(ls[ni], 32, 64);
        lq[ni] += __shfl_xor(lq[ni], 16, 64);
        lq[ni] += __shfl_xor(lq[ni], 32, 64);
    }
    if (lane < 16) {
        #pragma unroll
        for (int ni = 0; ni < 2; ++ni) {
            int ci = w * 32 + ni * 16 + l16;
            part[(size_t)blockIdx.x * 512 + ci]       = ls[ni];
            part[(size_t)blockIdx.x * 512 + 256 + ci] = lq[ni];
        }
    }
}

// Stage 2: one block per column c; reduce nb per-block partials, emit scale/shift.
__global__ void __launch_bounds__(256) bn_scale(const float* __restrict__ part, int nb,
                                                const float* __restrict__ gamma,
                                                const float* __restrict__ beta,
                                                float* __restrict__ scale,
                                                float* __restrict__ shift) {
    __shared__ float rs[256], rq[256];
    int t = threadIdx.x;
    int c = blockIdx.x;
    float s = 0.f, q = 0.f;
    for (int j = t; j < nb; j += 256) {
        s += part[(size_t)j * 512 + c];
        q += part[(size_t)j * 512 + 256 + c];
    }
    rs[t] = s; rq[t] = q;
    __syncthreads();
    for (int off = 128; off > 0; off >>= 1) {
        if (t < off) { rs[t] += rs[t + off]; rq[t] += rq[t + off]; }
        __syncthreads();
    }
    if (t == 0) {
        const float inv_n = 1.0f / (float)NN;
        float mu  = rs[0] * inv_n;
        float var = rq[0] * inv_n - mu * mu;
        float rstd = rsqrtf(var + 1e-5f);
        float sc = gamma[c] * rstd;
        scale[c] = sc;
        shift[c] = beta[c] - mu * sc;
    }
}

// ---- layer-2 collapse: z[n] = relu_bn(h[n]) . w2lw  (one wave per node) -----
__global__ void __launch_bounds__(256) bn_dot(const __bf16* __restrict__ h,
                                              const float* __restrict__ scale,
                                              const float* __restrict__ shift,
                                              const float* __restrict__ w2lw,
                                              float* __restrict__ z) {
    int tid = blockIdx.x * 256 + threadIdx.x;
    int n = tid >> 6;
    if (n >= NN) return;
    int l = tid & 63;
    int c4 = l * 4;
    bf16x4 a = *(const bf16x4*)&h[(size_t)n * HD + c4];
    float4 sc = *(const float4*)&scale[c4];
    float4 sh = *(const float4*)&shift[c4];
    float4 wv = *(const float4*)&w2lw[c4];
    float d = fmaxf((float)a[0] * sc.x + sh.x, 0.f) * wv.x
            + fmaxf((float)a[1] * sc.y + sh.y, 0.f) * wv.y
            + fmaxf((float)a[2] * sc.z + sh.z, 0.f) * wv.z
            + fmaxf((float)a[3] * sc.w + sh.w, 0.f) * wv.w;
    #pragma unroll
    for (int off = 32; off > 0; off >>= 1) d += __shfl_down(d, off, 64);
    if (l == 0) z[n] = d;
}

// ---- fused final: per-graph wave; lanes stride nodes; scalar edge loop ------
__global__ void __launch_bounds__(256) pool_fused(const float* __restrict__ z,
                                                  const float* __restrict__ selfn,
                                                  const float* __restrict__ b2lw,
                                                  const unsigned* __restrict__ row_start,
                                                  const int* __restrict__ ecol,
                                                  const float* __restrict__ enorm,
                                                  const unsigned* __restrict__ gstart,
                                                  const float* __restrict__ lb,
                                                  float* __restrict__ out) {
    int tid = blockIdx.x * 256 + threadIdx.x;
    int g = tid >> 6;
    if (g >= NG) return;
    int l = tid & 63;
    unsigned s0 = gstart[g], s1 = gstart[g + 1];
    float bb = *b2lw;
    float s = 0.f;
    for (unsigned i = s0 + l; i < s1; i += 64) {
        float d = selfn[i] * z[i] + bb;
        unsigned e0 = row_start[i], e1 = row_start[i + 1];
        for (unsigned e = e0; e < e1; ++e)
            d += enorm[e] * z[ecol[e]];
        s += d;
    }
    #pragma unroll
    for (int off = 32; off > 0; off >>= 1) s += __shfl_down(s, off, 64);
    if (l == 0) out[g] = s / fmaxf((float)(s1 - s0), 1.0f) + lb[0];
}

// ---- driver -----------------------------------------------------------------
extern "C" void kernel_launch(void* const* d_in, const int* in_sizes, int n_in,
                              void* d_out, int out_size, void* d_ws, size_t ws_size,
                              hipStream_t stream) {
    const int*   x     = (const int*)d_in[0];
    const int*   ei    = (const int*)d_in[1];
    const int*   batch = (const int*)d_in[2];
    const float* emb   = (const float*)d_in[3];
    const float* Ws    = (const float*)d_in[4];
    const float* bs    = (const float*)d_in[5];
    const float* gam   = (const float*)d_in[6];
    const float* bet   = (const float*)d_in[7];
    const float* lw    = (const float*)d_in[8];
    const float* lb    = (const float*)d_in[9];
    float* out = (float*)d_out;

    const int* src = ei;
    const int* dst = ei + NE;

    // workspace carve-up (256-B aligned)
    char* p = (char*)d_ws;
    size_t off = 0;
    auto carve = [&](size_t bytes) { void* r = p + off; off = (off + bytes + 255) & ~(size_t)255; return r; };
    __bf16*   buf0   = (__bf16*)carve((size_t)NN * HD * 2);   // conv0 (bf16)
    __bf16*   buf1   = (__bf16*)carve((size_t)NN * HD * 2);   // conv1 (bf16)
    __bf16*   xb     = (__bf16*)carve((size_t)NN * 64 * 2);   // x as bf16, pad 64
    __bf16*   dW0t   = (__bf16*)carve(HD * 64 * 2);
    __bf16*   Wt     = (__bf16*)carve((size_t)HD * HD * 2);   // layer-1 only
    float*    w2lw   = (float*)carve(HD * 4);
    float*    b2lw   = (float*)carve(256);
    unsigned* deg    = (unsigned*)carve(NN * 4);
    float*    dinv   = (float*)carve(NN * 4);
    float*    selfn  = (float*)carve(NN * 4);
    unsigned* csum   = (unsigned*)carve(256 * 4);
    unsigned* row_s  = (unsigned*)carve((NN + 1) * 4);
    unsigned* cursor = (unsigned*)carve(NN * 4);
    int*      ecol   = (int*)carve(NE * 4);
    float*    enorm  = (float*)carve(NE * 4);
    float*    part   = (float*)carve((size_t)GNB * 512 * 4);  // 3.2 MB, [blk][512]
    float*    scale  = (float*)carve(HD * 4);
    float*    shift  = (float*)carve(HD * 4);
    unsigned* gstart = (unsigned*)carve((NG + 1) * 4);
    float*    zbuf   = (float*)carve(NN * 4);
    (void)ws_size; (void)n_in; (void)in_sizes; (void)out_size;

    // params + weight transposes + deg zeroing + x->bf16, all in one dispatch
    prep_params<<<NF + 2 + HD + ZB + CVB, HD, 0, stream>>>(
        emb, Ws, bs, lw, dW0t, w2lw, b2lw, Wt, deg, x, xb);

    // degrees, CSR build with inline norm + graph bounds in tail blocks
    deg_kernel<<<(NE + 255) / 256, 256, 0, stream>>>(dst, deg, NE);
    chunk_sum_dinv<<<NCH, SCAN_CH, 0, stream>>>(deg, csum, dinv, selfn);
    chunk_apply<<<NCH, SCAN_CH, 0, stream>>>(deg, csum, row_s, cursor);
    csr_fill_gb<<<EB + (NG + 256) / 256, 256, 0, stream>>>(
        src, dst, dinv, cursor, ecol, enorm, batch, gstart);

    // layer 0: aggregate-into-LDS + encoder GEMM + BN stats, one kernel
    enc_fused<<<ENB, 512, 0, stream>>>(
        xb, dW0t, bs, selfn, row_s, ecol, enorm, buf0, part);
    bn_scale<<<HD, 256, 0, stream>>>(part, ENB, gam, bet, scale, shift);

    // layer 1 fully fused: aggregate relu_bn(conv0) into LDS + GEMM + stats
    gcn_fused<<<GNB, 512, 0, stream>>>(
        buf0, scale, shift, Wt, bs + HD, selfn, row_s, ecol, enorm, buf1, part);
    bn_scale<<<HD, 256, 0, stream>>>(part, GNB, gam + HD, bet + HD, scale, shift);

    // layer 2 (collapsed): z = relu_bn(conv1)@(W2 lw); fused agg+pool
    bn_dot<<<(NN * 64 + 255) / 256, 256, 0, stream>>>(buf1, scale, shift, w2lw, zbuf);
    pool_fused<<<(NG * 64 + 255) / 256, 256, 0, stream>>>(
        zbuf, selfn, b2lw, row_s, ecol, enorm, gstart, lb, out);
}